// Round 3
// baseline (365.372 us; speedup 1.0000x reference)
//
#include <hip/hip_runtime.h>

// GRUObservationCellLogvar — R3: split prep/gemm through ws, barrier-free MFMA kernel.
// N=500000, N_OBS=200000, D=32, H=128, P=4
// out = [ h_updated (500000*128) | losses (200000*32) ] fp32
//
// ws layout: [0, 192KB)   Bpk  — bf16 B-fragments (k_prepack)
//            [256KB, +102.4MB) A — bf16 A-fragments, 3125 tiles x 32KB (k_prep)
//
// Order: k_prepack, k_copy (warms L3 with h), k_prep (writes A), k_gemm (A L3-hot).
// Fallback to fused k_main_fb (R2, verified) if ws_size too small.

typedef __attribute__((ext_vector_type(8))) short bf16x8;
typedef __attribute__((ext_vector_type(4))) float f32x4;

__device__ inline unsigned short f2bf(float x) {
    union { float f; unsigned int u; } v; v.f = x;
    unsigned int r = (v.u + 0x7fffu + ((v.u >> 16) & 1u)) >> 16;  // RNE
    return (unsigned short)r;
}

// ---- B prepack: 98304 bf16 = 8 waves * 24 frags * 64 lanes * 8 ----
__global__ __launch_bounds__(256) void k_prepack(const float* __restrict__ W_ih,
                                                 const float* __restrict__ W_hh,
                                                 unsigned short* __restrict__ B) {
    const int i = blockIdx.x * 256 + threadIdx.x;        // 0 .. 98303
    const int w    = i / 12288;
    const int rem  = i - w * 12288;
    const int f    = rem >> 9;
    const int rem2 = rem & 511;
    const int l    = rem2 >> 3;
    const int j    = rem2 & 7;
    const int c    = w * 16 + (l & 15);
    const int ko   = (l >> 4) * 8 + j;
    float val;
    if (f < 8) {
        const int k = f * 32 + ko;
        val = (k < 128) ? W_ih[c * 128 + k] : W_hh[c * 128 + (k - 128)];
    } else if (f < 16) {
        const int k = (f - 8) * 32 + ko;
        val = (k < 128) ? W_ih[(128 + c) * 128 + k] : W_hh[(128 + c) * 128 + (k - 128)];
    } else if (f < 20) {
        const int k = (f - 16) * 32 + ko;
        val = W_ih[(256 + c) * 128 + k];
    } else {
        const int k = (f - 20 + 4) * 32 + ko;
        val = W_hh[(256 + c) * 128 + (k - 128)];
    }
    B[i] = f2bf(val);
}

__global__ __launch_bounds__(256) void k_copy(const float4* __restrict__ src,
                                              float4* __restrict__ dst, long n4) {
    long i = (long)blockIdx.x * blockDim.x + threadIdx.x;
    long stride = (long)gridDim.x * blockDim.x;
    for (; i < n4; i += stride) dst[i] = src[i];
}

// ---- prep: losses + A-fragments (bf16) -> ws. 64 rows/block, 512 thr ----
__global__ __launch_bounds__(512) void k_prep(
    const float* __restrict__ h,
    const float* __restrict__ p,
    const float* __restrict__ X_obs,
    const float* __restrict__ M_obs,
    const int*   __restrict__ i_obs,
    const float* __restrict__ w_prep,
    const float* __restrict__ bias_prep,
    float* __restrict__ out_losses,
    unsigned short* __restrict__ A)
{
    __shared__ unsigned short sA[4 * 8 * 64 * 8];   // 32 KB
    __shared__ int sIdx[64];

    const int tid  = threadIdx.x;
    const int row0 = blockIdx.x * 64;

    if (tid < 64) sIdx[tid] = i_obs[row0 + tid];
    __syncthreads();

    {
        const int d = tid & 31;
        float wp[16], bp[4];
        #pragma unroll
        for (int t = 0; t < 16; ++t) wp[t] = w_prep[d * 16 + t];
        #pragma unroll
        for (int t = 0; t < 4; ++t) bp[t] = bias_prep[d * 4 + t];

        const int ksA     = d >> 3;
        const int lane16A = (d >> 1) & 3;
        const int j0A     = (d & 1) * 4;

        #pragma unroll
        for (int pass = 0; pass < 4; ++pass) {
            const int r   = pass * 16 + (tid >> 5);
            const int row = row0 + r;
            const int idx = sIdx[r];
            const float mean   = p[(size_t)idx * 64 + d];
            const float logvar = p[(size_t)idx * 64 + 32 + d];
            const float X = X_obs[(size_t)row * 32 + d];
            const float M = M_obs[(size_t)row * 32 + d];
            const float lv  = fminf(fmaxf(logvar, -10.f), 10.f);
            const float sig = fminf(fmaxf(expf(0.5f * lv), 1e-6f), 1e6f);
            const float err = fminf(fmaxf((X - mean) / sig, -1e6f), 1e6f);
            out_losses[(size_t)row * 32 + d] =
                0.5f * ((err * err + lv + 1.8378770664093453f) * M);
            ushort4 u;
            {
                float g0 = fmaf(X, wp[0], fmaf(mean, wp[4], fmaf(lv, wp[8],  fmaf(err, wp[12], bp[0]))));
                float g1 = fmaf(X, wp[1], fmaf(mean, wp[5], fmaf(lv, wp[9],  fmaf(err, wp[13], bp[1]))));
                float g2 = fmaf(X, wp[2], fmaf(mean, wp[6], fmaf(lv, wp[10], fmaf(err, wp[14], bp[2]))));
                float g3 = fmaf(X, wp[3], fmaf(mean, wp[7], fmaf(lv, wp[11], fmaf(err, wp[15], bp[3]))));
                u.x = f2bf(fmaxf(g0, 0.f) * M);
                u.y = f2bf(fmaxf(g1, 0.f) * M);
                u.z = f2bf(fmaxf(g2, 0.f) * M);
                u.w = f2bf(fmaxf(g3, 0.f) * M);
            }
            const int mt   = r >> 4;
            const int lane = (r & 15) + lane16A * 16;
            *reinterpret_cast<ushort4*>(&sA[((mt * 8 + ksA) * 64 + lane) * 8 + j0A]) = u;
        }

        const int c4      = tid & 31;
        const int ksH     = 4 + (c4 >> 3);
        const int lane16H = (c4 >> 1) & 3;
        const int j0H     = (c4 & 1) * 4;
        #pragma unroll
        for (int pass = 0; pass < 4; ++pass) {
            const int r = pass * 16 + (tid >> 5);
            const float4 v = *reinterpret_cast<const float4*>(h + (size_t)sIdx[r] * 128 + c4 * 4);
            ushort4 u;
            u.x = f2bf(v.x); u.y = f2bf(v.y); u.z = f2bf(v.z); u.w = f2bf(v.w);
            const int mt   = r >> 4;
            const int lane = (r & 15) + lane16H * 16;
            *reinterpret_cast<ushort4*>(&sA[((mt * 8 + ksH) * 64 + lane) * 8 + j0H]) = u;
        }
    }
    __syncthreads();

    // coalesced dump: 32 KB = 2048 uint4
    const uint4* s4 = reinterpret_cast<const uint4*>(sA);
    uint4* g4 = reinterpret_cast<uint4*>(A + (size_t)blockIdx.x * 16384);
    #pragma unroll
    for (int i = 0; i < 4; ++i) g4[i * 512 + tid] = s4[i * 512 + tid];
}

// ---- gemm: barrier-free, LDS-free. 64 rows/block, 8 waves x 16 cols ----
__global__ __launch_bounds__(512) void k_gemm(
    const float* __restrict__ h,
    const int*   __restrict__ i_obs,
    const unsigned short* __restrict__ A,
    const unsigned short* __restrict__ Bpk,
    const float* __restrict__ b_ih,
    const float* __restrict__ b_hh,
    float* __restrict__ out_h)
{
    const int tid  = threadIdx.x;
    const int wid  = tid >> 6;
    const int lane = tid & 63;
    const int c    = wid * 16 + (lane & 15);
    const int row0 = blockIdx.x * 64;

    bf16x8 breg[24];
    const bf16x8* bsrc = reinterpret_cast<const bf16x8*>(Bpk) + wid * 1536;
    #pragma unroll
    for (int f = 0; f < 24; ++f) breg[f] = bsrc[f * 64 + lane];

    const float bR  = b_ih[c]       + b_hh[c];
    const float bZ  = b_ih[128 + c] + b_hh[128 + c];
    const float bIN = b_ih[256 + c];
    const float bHN = b_hh[256 + c];

    const bf16x8* aptr = reinterpret_cast<const bf16x8*>(A) + (size_t)blockIdx.x * 2048;

    #pragma unroll
    for (int mt = 0; mt < 4; ++mt) {
        f32x4 accR = {0.f, 0.f, 0.f, 0.f};
        f32x4 accZ = {0.f, 0.f, 0.f, 0.f};
        f32x4 accIN = {0.f, 0.f, 0.f, 0.f};
        f32x4 accHN = {0.f, 0.f, 0.f, 0.f};
        #pragma unroll
        for (int ks = 0; ks < 8; ++ks) {
            const bf16x8 af = aptr[(mt * 8 + ks) * 64 + lane];
            accR = __builtin_amdgcn_mfma_f32_16x16x32_bf16(af, breg[ks],     accR, 0, 0, 0);
            accZ = __builtin_amdgcn_mfma_f32_16x16x32_bf16(af, breg[8 + ks], accZ, 0, 0, 0);
            if (ks < 4) accIN = __builtin_amdgcn_mfma_f32_16x16x32_bf16(af, breg[16 + ks], accIN, 0, 0, 0);
            else        accHN = __builtin_amdgcn_mfma_f32_16x16x32_bf16(af, breg[16 + ks], accHN, 0, 0, 0);
        }
        const int rbase = mt * 16 + (lane >> 4) * 4;
        #pragma unroll
        for (int reg = 0; reg < 4; ++reg) {
            const int idx  = i_obs[row0 + rbase + reg];
            const float hp = h[(size_t)idx * 128 + c];
            const float xr  = accR[reg]  + bR;
            const float xz  = accZ[reg]  + bZ;
            const float xin = accIN[reg] + bIN;
            const float xhn = accHN[reg] + bHN;
            const float rg = 1.f / (1.f + expf(-xr));
            const float zg = 1.f / (1.f + expf(-xz));
            const float ng = tanhf(fmaf(rg, xhn, xin));
            out_h[(size_t)idx * 128 + c] = fmaf(zg, hp - ng, ng);
        }
    }
}

// ---- fallback (verified R2 fused kernel) for small ws ----
__global__ __launch_bounds__(512) void k_main_fb(
    const float* __restrict__ h,
    const float* __restrict__ p,
    const float* __restrict__ X_obs,
    const float* __restrict__ M_obs,
    const int*   __restrict__ i_obs,
    const float* __restrict__ w_prep,
    const float* __restrict__ bias_prep,
    const unsigned short* __restrict__ Bpk,
    const float* __restrict__ b_ih,
    const float* __restrict__ b_hh,
    float* __restrict__ out_h,
    float* __restrict__ out_losses)
{
    __shared__ unsigned short sA[4 * 8 * 64 * 8];
    __shared__ int sIdx[64];
    const int tid  = threadIdx.x;
    const int row0 = blockIdx.x * 64;
    if (tid < 64) sIdx[tid] = i_obs[row0 + tid];
    __syncthreads();
    {
        const int d = tid & 31;
        float wp[16], bp[4];
        #pragma unroll
        for (int t = 0; t < 16; ++t) wp[t] = w_prep[d * 16 + t];
        #pragma unroll
        for (int t = 0; t < 4; ++t) bp[t] = bias_prep[d * 4 + t];
        const int ksA     = d >> 3;
        const int lane16A = (d >> 1) & 3;
        const int j0A     = (d & 1) * 4;
        #pragma unroll
        for (int pass = 0; pass < 4; ++pass) {
            const int r   = pass * 16 + (tid >> 5);
            const int row = row0 + r;
            const int idx = sIdx[r];
            const float mean   = p[(size_t)idx * 64 + d];
            const float logvar = p[(size_t)idx * 64 + 32 + d];
            const float X = X_obs[(size_t)row * 32 + d];
            const float M = M_obs[(size_t)row * 32 + d];
            const float lv  = fminf(fmaxf(logvar, -10.f), 10.f);
            const float sig = fminf(fmaxf(expf(0.5f * lv), 1e-6f), 1e6f);
            const float err = fminf(fmaxf((X - mean) / sig, -1e6f), 1e6f);
            out_losses[(size_t)row * 32 + d] =
                0.5f * ((err * err + lv + 1.8378770664093453f) * M);
            ushort4 u;
            float g0 = fmaf(X, wp[0], fmaf(mean, wp[4], fmaf(lv, wp[8],  fmaf(err, wp[12], bp[0]))));
            float g1 = fmaf(X, wp[1], fmaf(mean, wp[5], fmaf(lv, wp[9],  fmaf(err, wp[13], bp[1]))));
            float g2 = fmaf(X, wp[2], fmaf(mean, wp[6], fmaf(lv, wp[10], fmaf(err, wp[14], bp[2]))));
            float g3 = fmaf(X, wp[3], fmaf(mean, wp[7], fmaf(lv, wp[11], fmaf(err, wp[15], bp[3]))));
            u.x = f2bf(fmaxf(g0, 0.f) * M);
            u.y = f2bf(fmaxf(g1, 0.f) * M);
            u.z = f2bf(fmaxf(g2, 0.f) * M);
            u.w = f2bf(fmaxf(g3, 0.f) * M);
            const int mt   = r >> 4;
            const int lane = (r & 15) + lane16A * 16;
            *reinterpret_cast<ushort4*>(&sA[((mt * 8 + ksA) * 64 + lane) * 8 + j0A]) = u;
        }
        const int c4      = tid & 31;
        const int ksH     = 4 + (c4 >> 3);
        const int lane16H = (c4 >> 1) & 3;
        const int j0H     = (c4 & 1) * 4;
        #pragma unroll
        for (int pass = 0; pass < 4; ++pass) {
            const int r = pass * 16 + (tid >> 5);
            const float4 v = *reinterpret_cast<const float4*>(h + (size_t)sIdx[r] * 128 + c4 * 4);
            ushort4 u;
            u.x = f2bf(v.x); u.y = f2bf(v.y); u.z = f2bf(v.z); u.w = f2bf(v.w);
            const int mt   = r >> 4;
            const int lane = (r & 15) + lane16H * 16;
            *reinterpret_cast<ushort4*>(&sA[((mt * 8 + ksH) * 64 + lane) * 8 + j0H]) = u;
        }
    }
    __syncthreads();
    const int wid  = tid >> 6;
    const int lane = tid & 63;
    const int c    = wid * 16 + (lane & 15);
    bf16x8 breg[24];
    const bf16x8* bsrc = reinterpret_cast<const bf16x8*>(Bpk) + wid * 1536;
    #pragma unroll
    for (int f = 0; f < 24; ++f) breg[f] = bsrc[f * 64 + lane];
    const float bR  = b_ih[c]       + b_hh[c];
    const float bZ  = b_ih[128 + c] + b_hh[128 + c];
    const float bIN = b_ih[256 + c];
    const float bHN = b_hh[256 + c];
    const bf16x8* aptr = reinterpret_cast<const bf16x8*>(sA);
    #pragma unroll
    for (int mt = 0; mt < 4; ++mt) {
        f32x4 accR = {0.f, 0.f, 0.f, 0.f};
        f32x4 accZ = {0.f, 0.f, 0.f, 0.f};
        f32x4 accIN = {0.f, 0.f, 0.f, 0.f};
        f32x4 accHN = {0.f, 0.f, 0.f, 0.f};
        #pragma unroll
        for (int ks = 0; ks < 8; ++ks) {
            const bf16x8 af = aptr[(mt * 8 + ks) * 64 + lane];
            accR = __builtin_amdgcn_mfma_f32_16x16x32_bf16(af, breg[ks],     accR, 0, 0, 0);
            accZ = __builtin_amdgcn_mfma_f32_16x16x32_bf16(af, breg[8 + ks], accZ, 0, 0, 0);
            if (ks < 4) accIN = __builtin_amdgcn_mfma_f32_16x16x32_bf16(af, breg[16 + ks], accIN, 0, 0, 0);
            else        accHN = __builtin_amdgcn_mfma_f32_16x16x32_bf16(af, breg[16 + ks], accHN, 0, 0, 0);
        }
        const int rbase = mt * 16 + (lane >> 4) * 4;
        #pragma unroll
        for (int reg = 0; reg < 4; ++reg) {
            const int idx  = i_obs[row0 + rbase + reg];
            const float hp = h[(size_t)idx * 128 + c];
            const float xr  = accR[reg]  + bR;
            const float xz  = accZ[reg]  + bZ;
            const float xin = accIN[reg] + bIN;
            const float xhn = accHN[reg] + bHN;
            const float rg = 1.f / (1.f + expf(-xr));
            const float zg = 1.f / (1.f + expf(-xz));
            const float ng = tanhf(fmaf(rg, xhn, xin));
            out_h[(size_t)idx * 128 + c] = fmaf(zg, hp - ng, ng);
        }
    }
}

extern "C" void kernel_launch(void* const* d_in, const int* in_sizes, int n_in,
                              void* d_out, int out_size, void* d_ws, size_t ws_size,
                              hipStream_t stream) {
    const float* h         = (const float*)d_in[0];
    const float* p         = (const float*)d_in[1];
    const float* X_obs     = (const float*)d_in[2];
    const float* M_obs     = (const float*)d_in[3];
    const int*   i_obs     = (const int*)d_in[4];
    const float* w_prep    = (const float*)d_in[5];
    const float* bias_prep = (const float*)d_in[6];
    const float* W_ih      = (const float*)d_in[7];
    const float* W_hh      = (const float*)d_in[8];
    const float* b_ih      = (const float*)d_in[9];
    const float* b_hh      = (const float*)d_in[10];

    const int Nh   = in_sizes[0] / 128;   // 500000
    const int NOBS = in_sizes[4];         // 200000
    const int NT   = NOBS / 64;           // 3125 tiles

    float* out_h      = (float*)d_out;
    float* out_losses = out_h + (size_t)Nh * 128;

    unsigned short* Bpk = (unsigned short*)d_ws;                       // 192 KB
    unsigned short* A   = (unsigned short*)((char*)d_ws + (256 << 10)); // 102.4 MB
    const size_t ws_needed = (256 << 10) + (size_t)NT * 16384 * 2;

    hipLaunchKernelGGL(k_prepack, dim3(98304 / 256), dim3(256), 0, stream,
                       W_ih, W_hh, Bpk);

    long n4 = (long)Nh * 128 / 4;
    hipLaunchKernelGGL(k_copy, dim3(4096), dim3(256), 0, stream,
                       (const float4*)h, (float4*)out_h, n4);

    if (ws_size >= ws_needed) {
        hipLaunchKernelGGL(k_prep, dim3(NT), dim3(512), 0, stream,
                           h, p, X_obs, M_obs, i_obs, w_prep, bias_prep,
                           out_losses, A);
        hipLaunchKernelGGL(k_gemm, dim3(NT), dim3(512), 0, stream,
                           h, i_obs, A, Bpk, b_ih, b_hh, out_h);
    } else {
        hipLaunchKernelGGL(k_main_fb, dim3(NT), dim3(512), 0, stream,
                           h, p, X_obs, M_obs, i_obs, w_prep, bias_prep, Bpk,
                           b_ih, b_hh, out_h, out_losses);
    }
}

// Round 4
// 266.352 us; speedup vs baseline: 1.3718x; 1.3718x over previous
//
#include <hip/hip_runtime.h>

// GRUObservationCellLogvar — R4: fused heterogeneous kernel.
// N=500000, N_OBS=200000, D=32, H=128, P=4
// out = [ h_updated (500000*128) | losses (200000*32) ] fp32
//
// Launch sequence:
//   hipMemsetAsync(flags, 0)       flags: 1 byte per h-row
//   k_prepack                      W -> bf16 B-fragments (ws)
//   k_flag                         flags[i_obs[i]] = 1
//   k_het (4687 blocks):           bid%3==2 -> copy role (unobserved h rows only)
//                                  else     -> main role (R2 fused GRU, fast math)
// Disjoint write sets (flags) => copy/main co-scheduling is race-free and the
// streaming copy soaks HBM slots left idle by the latency-bound main blocks.

typedef __attribute__((ext_vector_type(8))) short bf16x8;
typedef __attribute__((ext_vector_type(4))) float f32x4;

__device__ inline unsigned short f2bf_rne(float x) {
    union { float f; unsigned int u; } v; v.f = x;
    unsigned int r = (v.u + 0x7fffu + ((v.u >> 16) & 1u)) >> 16;
    return (unsigned short)r;
}
__device__ inline unsigned short f2bf_tr(float x) {          // truncate (1 instr)
    return (unsigned short)(__float_as_uint(x) >> 16);
}
__device__ inline float bf2f(unsigned short u) {
    return __uint_as_float(((unsigned int)u) << 16);
}
__device__ inline float fast_sigmoid(float x) {
    return __builtin_amdgcn_rcpf(1.f + __expf(-x));
}
__device__ inline float fast_tanh(float x) {
    const float a = fabsf(x);
    const float t = __expf(-2.f * a);
    const float r = (1.f - t) * __builtin_amdgcn_rcpf(1.f + t);
    return __builtin_copysignf(r, x);
}

// ---- B prepack: 98304 bf16 = 8 waves * 24 frags * 64 lanes * 8 (RNE) ----
__global__ __launch_bounds__(256) void k_prepack(const float* __restrict__ W_ih,
                                                 const float* __restrict__ W_hh,
                                                 unsigned short* __restrict__ B) {
    const int i = blockIdx.x * 256 + threadIdx.x;
    const int w    = i / 12288;
    const int rem  = i - w * 12288;
    const int f    = rem >> 9;
    const int rem2 = rem & 511;
    const int l    = rem2 >> 3;
    const int j    = rem2 & 7;
    const int c    = w * 16 + (l & 15);
    const int ko   = (l >> 4) * 8 + j;
    float val;
    if (f < 8) {
        const int k = f * 32 + ko;
        val = (k < 128) ? W_ih[c * 128 + k] : W_hh[c * 128 + (k - 128)];
    } else if (f < 16) {
        const int k = (f - 8) * 32 + ko;
        val = (k < 128) ? W_ih[(128 + c) * 128 + k] : W_hh[(128 + c) * 128 + (k - 128)];
    } else if (f < 20) {
        const int k = (f - 16) * 32 + ko;
        val = W_ih[(256 + c) * 128 + k];
    } else {
        const int k = (f - 20 + 4) * 32 + ko;
        val = W_hh[(256 + c) * 128 + (k - 128)];
    }
    B[i] = f2bf_rne(val);
}

__global__ __launch_bounds__(256) void k_flag(const int* __restrict__ i_obs,
                                              unsigned char* __restrict__ flags, int n) {
    const int i = blockIdx.x * 256 + threadIdx.x;
    if (i < n) flags[i_obs[i]] = 1;
}

// plain full copy (fallback path only)
__global__ __launch_bounds__(256) void k_copy(const float4* __restrict__ src,
                                              float4* __restrict__ dst, long n4) {
    long i = (long)blockIdx.x * blockDim.x + threadIdx.x;
    long stride = (long)gridDim.x * blockDim.x;
    for (; i < n4; i += stride) dst[i] = src[i];
}

// ---------------- main role: fused prep + dual-GEMM + GRU ----------------
__device__ void main_role(int mbid,
    const float* __restrict__ h, const float* __restrict__ p,
    const float* __restrict__ X_obs, const float* __restrict__ M_obs,
    const int* __restrict__ i_obs,
    const float* __restrict__ w_prep, const float* __restrict__ bias_prep,
    const unsigned short* __restrict__ Bpk,
    const float* __restrict__ b_ih, const float* __restrict__ b_hh,
    float* __restrict__ out_h, float* __restrict__ out_losses,
    unsigned short* sA, int* sIdx)
{
    const int tid  = threadIdx.x;
    const int row0 = mbid * 64;

    if (tid < 64) sIdx[tid] = i_obs[row0 + tid];
    __syncthreads();

    {
        const int d = tid & 31;
        float wp[16], bp[4];
        #pragma unroll
        for (int t = 0; t < 16; ++t) wp[t] = w_prep[d * 16 + t];
        #pragma unroll
        for (int t = 0; t < 4; ++t) bp[t] = bias_prep[d * 4 + t];

        const int ksA     = d >> 3;
        const int lane16A = (d >> 1) & 3;
        const int j0A     = (d & 1) * 4;

        #pragma unroll
        for (int pass = 0; pass < 4; ++pass) {
            const int r   = pass * 16 + (tid >> 5);
            const int row = row0 + r;
            const int idx = sIdx[r];
            const float mean   = p[(size_t)idx * 64 + d];
            const float logvar = p[(size_t)idx * 64 + 32 + d];
            const float X = X_obs[(size_t)row * 32 + d];
            const float M = M_obs[(size_t)row * 32 + d];
            const float lv      = fminf(fmaxf(logvar, -10.f), 10.f);
            const float inv_sig = __expf(-0.5f * lv);          // 1/sigma, clips inactive
            const float err     = fminf(fmaxf((X - mean) * inv_sig, -1e6f), 1e6f);
            out_losses[(size_t)row * 32 + d] =
                0.5f * ((err * err + lv + 1.8378770664093453f) * M);
            ushort4 u;
            {
                float g0 = fmaf(X, wp[0], fmaf(mean, wp[4], fmaf(lv, wp[8],  fmaf(err, wp[12], bp[0]))));
                float g1 = fmaf(X, wp[1], fmaf(mean, wp[5], fmaf(lv, wp[9],  fmaf(err, wp[13], bp[1]))));
                float g2 = fmaf(X, wp[2], fmaf(mean, wp[6], fmaf(lv, wp[10], fmaf(err, wp[14], bp[2]))));
                float g3 = fmaf(X, wp[3], fmaf(mean, wp[7], fmaf(lv, wp[11], fmaf(err, wp[15], bp[3]))));
                u.x = f2bf_tr(fmaxf(g0, 0.f) * M);
                u.y = f2bf_tr(fmaxf(g1, 0.f) * M);
                u.z = f2bf_tr(fmaxf(g2, 0.f) * M);
                u.w = f2bf_tr(fmaxf(g3, 0.f) * M);
            }
            const int mt   = r >> 4;
            const int lane = (r & 15) + lane16A * 16;
            *reinterpret_cast<ushort4*>(&sA[((mt * 8 + ksA) * 64 + lane) * 8 + j0A]) = u;
        }

        const int c4      = tid & 31;
        const int ksH     = 4 + (c4 >> 3);
        const int lane16H = (c4 >> 1) & 3;
        const int j0H     = (c4 & 1) * 4;
        #pragma unroll
        for (int pass = 0; pass < 4; ++pass) {
            const int r = pass * 16 + (tid >> 5);
            const float4 v = *reinterpret_cast<const float4*>(h + (size_t)sIdx[r] * 128 + c4 * 4);
            ushort4 u;
            u.x = f2bf_tr(v.x); u.y = f2bf_tr(v.y); u.z = f2bf_tr(v.z); u.w = f2bf_tr(v.w);
            const int mt   = r >> 4;
            const int lane = (r & 15) + lane16H * 16;
            *reinterpret_cast<ushort4*>(&sA[((mt * 8 + ksH) * 64 + lane) * 8 + j0H]) = u;
        }
    }
    __syncthreads();

    // ---- MFMA phase ----
    const int wid  = tid >> 6;
    const int lane = tid & 63;
    const int c    = wid * 16 + (lane & 15);

    bf16x8 breg[24];
    const bf16x8* bsrc = reinterpret_cast<const bf16x8*>(Bpk) + wid * 1536;
    #pragma unroll
    for (int f = 0; f < 24; ++f) breg[f] = bsrc[f * 64 + lane];

    const float bR  = b_ih[c]       + b_hh[c];
    const float bZ  = b_ih[128 + c] + b_hh[128 + c];
    const float bIN = b_ih[256 + c];
    const float bHN = b_hh[256 + c];

    const bf16x8* aptr = reinterpret_cast<const bf16x8*>(sA);
    // epilogue h_old lookup coords (k = 128 + c)
    const int ksE  = 4 + (c >> 5);
    const int l16E = ((c >> 3) & 3) * 16;
    const int jE   = c & 7;

    #pragma unroll
    for (int mt = 0; mt < 4; ++mt) {
        f32x4 accR = {0.f, 0.f, 0.f, 0.f};
        f32x4 accZ = {0.f, 0.f, 0.f, 0.f};
        f32x4 accIN = {0.f, 0.f, 0.f, 0.f};
        f32x4 accHN = {0.f, 0.f, 0.f, 0.f};
        #pragma unroll
        for (int ks = 0; ks < 8; ++ks) {
            const bf16x8 af = aptr[(mt * 8 + ks) * 64 + lane];
            accR = __builtin_amdgcn_mfma_f32_16x16x32_bf16(af, breg[ks],     accR, 0, 0, 0);
            accZ = __builtin_amdgcn_mfma_f32_16x16x32_bf16(af, breg[8 + ks], accZ, 0, 0, 0);
            if (ks < 4) accIN = __builtin_amdgcn_mfma_f32_16x16x32_bf16(af, breg[16 + ks], accIN, 0, 0, 0);
            else        accHN = __builtin_amdgcn_mfma_f32_16x16x32_bf16(af, breg[16 + ks], accHN, 0, 0, 0);
        }
        const int r15b = (lane >> 4) * 4;
        #pragma unroll
        for (int reg = 0; reg < 4; ++reg) {
            const int r15 = r15b + reg;
            const int idx = sIdx[mt * 16 + r15];
            const float hp = bf2f(sA[((mt * 8 + ksE) * 64 + r15 + l16E) * 8 + jE]);
            const float xr  = accR[reg]  + bR;
            const float xz  = accZ[reg]  + bZ;
            const float xin = accIN[reg] + bIN;
            const float xhn = accHN[reg] + bHN;
            const float rg = fast_sigmoid(xr);
            const float zg = fast_sigmoid(xz);
            const float ng = fast_tanh(fmaf(rg, xhn, xin));
            out_h[(size_t)idx * 128 + c] = fmaf(zg, hp - ng, ng);
        }
    }
}

// ---------------- copy role: unobserved rows only ----------------
__device__ void copy_role(int cbid, int ncopy,
                          const float4* __restrict__ src, float4* __restrict__ dst,
                          const unsigned char* __restrict__ flags, long n4)
{
    const long per = (n4 + ncopy - 1) / ncopy;
    const long lo  = (long)cbid * per;
    long hi = lo + per; if (hi > n4) hi = n4;
    #pragma unroll 4
    for (long i = lo + threadIdx.x; i < hi; i += 512) {
        const int row = (int)(i >> 5);            // 32 float4 per 128-col row
        if (!flags[row]) dst[i] = src[i];
    }
}

__global__ __launch_bounds__(512) void k_het(
    const float* __restrict__ h, const float* __restrict__ p,
    const float* __restrict__ X_obs, const float* __restrict__ M_obs,
    const int* __restrict__ i_obs,
    const float* __restrict__ w_prep, const float* __restrict__ bias_prep,
    const unsigned short* __restrict__ Bpk,
    const float* __restrict__ b_ih, const float* __restrict__ b_hh,
    float* __restrict__ out_h, float* __restrict__ out_losses,
    const unsigned char* __restrict__ flags, long n4, int ncopy)
{
    __shared__ unsigned short sA[4 * 8 * 64 * 8];   // 32 KB
    __shared__ int sIdx[64];

    const int bid = blockIdx.x;
    if (ncopy > 0) {
        const int r = bid % 3;
        if (r == 2) {
            copy_role(bid / 3, ncopy, (const float4*)h, (float4*)out_h, flags, n4);
            return;
        }
        main_role((bid / 3) * 2 + r, h, p, X_obs, M_obs, i_obs, w_prep, bias_prep,
                  Bpk, b_ih, b_hh, out_h, out_losses, sA, sIdx);
    } else {
        main_role(bid, h, p, X_obs, M_obs, i_obs, w_prep, bias_prep,
                  Bpk, b_ih, b_hh, out_h, out_losses, sA, sIdx);
    }
}

extern "C" void kernel_launch(void* const* d_in, const int* in_sizes, int n_in,
                              void* d_out, int out_size, void* d_ws, size_t ws_size,
                              hipStream_t stream) {
    const float* h         = (const float*)d_in[0];
    const float* p         = (const float*)d_in[1];
    const float* X_obs     = (const float*)d_in[2];
    const float* M_obs     = (const float*)d_in[3];
    const int*   i_obs     = (const int*)d_in[4];
    const float* w_prep    = (const float*)d_in[5];
    const float* bias_prep = (const float*)d_in[6];
    const float* W_ih      = (const float*)d_in[7];
    const float* W_hh      = (const float*)d_in[8];
    const float* b_ih      = (const float*)d_in[9];
    const float* b_hh      = (const float*)d_in[10];

    const int Nh   = in_sizes[0] / 128;   // 500000
    const int NOBS = in_sizes[4];         // 200000
    const int NT   = NOBS / 64;           // 3125 main blocks
    const long n4  = (long)Nh * 128 / 4;  // 16M float4

    float* out_h      = (float*)d_out;
    float* out_losses = out_h + (size_t)Nh * 128;

    unsigned short* Bpk   = (unsigned short*)d_ws;                    // 192 KB
    unsigned char*  flags = (unsigned char*)d_ws + (256 << 10);       // Nh bytes
    const size_t ws_needed = (256 << 10) + (size_t)Nh;

    hipLaunchKernelGGL(k_prepack, dim3(98304 / 256), dim3(256), 0, stream,
                       W_ih, W_hh, Bpk);

    if (ws_size >= ws_needed) {
        hipMemsetAsync(flags, 0, (size_t)Nh, stream);
        hipLaunchKernelGGL(k_flag, dim3((NOBS + 255) / 256), dim3(256), 0, stream,
                           i_obs, flags, NOBS);
        // interleaved 2:1 main:copy — main mbid 0..NT-1, copy cbid 0..NCOPY-1
        const int NCOPY = (NT - 1) / 2;           // 1562
        const int grid  = NT + NCOPY;             // 4687
        hipLaunchKernelGGL(k_het, dim3(grid), dim3(512), 0, stream,
                           h, p, X_obs, M_obs, i_obs, w_prep, bias_prep, Bpk,
                           b_ih, b_hh, out_h, out_losses, flags, n4, NCOPY);
    } else {
        // fallback: serialized full copy + main-only het
        hipLaunchKernelGGL(k_copy, dim3(4096), dim3(256), 0, stream,
                           (const float4*)h, (float4*)out_h, n4);
        hipLaunchKernelGGL(k_het, dim3(NT), dim3(512), 0, stream,
                           h, p, X_obs, M_obs, i_obs, w_prep, bias_prep, Bpk,
                           b_ih, b_hh, out_h, out_losses, (const unsigned char*)nullptr,
                           n4, 0);
    }
}